// Round 1
// baseline (3182.774 us; speedup 1.0000x reference)
//
#include <hip/hip_runtime.h>

constexpr int Dd = 128;
constexpr float BN_EPS = 1e-12f;
constexpr float NEG_SLOPE = 0.2f;

// ---------------- zero fill (float4 granularity) ----------------
__global__ __launch_bounds__(256) void zero_kernel(float* __restrict__ p, int n4) {
    int i = blockIdx.x * 256 + threadIdx.x;
    if (i < n4) ((float4*)p)[i] = make_float4(0.f, 0.f, 0.f, 0.f);
}

// ---------------- fused GEMM: h = x@W, hs = h@a_src, hd = h@a_dst ----------------
// block: 256 threads, 64 rows x 128 cols, K chunked by 32.
__global__ __launch_bounds__(256) void gemm_fused(
    const float* __restrict__ X, const float* __restrict__ W,
    const float* __restrict__ asrc, const float* __restrict__ adst,
    float* __restrict__ H, float* __restrict__ hs, float* __restrict__ hd, int N)
{
    __shared__ float Xs[64][36];     // +4 pad: float4-aligned stores, conflict-free reads
    __shared__ float Wl[32][128];

    const int t  = threadIdx.x;
    const int tx = t & 15, ty = t >> 4;
    const int row0 = blockIdx.x * 64;
    const int c0 = tx * 4, c1 = 64 + tx * 4;   // two float4 column groups (2-way LDS = free)

    const float4 aS0 = *(const float4*)&asrc[c0];
    const float4 aS1 = *(const float4*)&asrc[c1];
    const float4 aD0 = *(const float4*)&adst[c0];
    const float4 aD1 = *(const float4*)&adst[c1];

    float acc[4][8];
#pragma unroll
    for (int r = 0; r < 4; ++r)
#pragma unroll
        for (int c = 0; c < 8; ++c) acc[r][c] = 0.f;

    for (int kc = 0; kc < 4; ++kc) {
        // stage X tile: 64 rows x 32 k
        {
            int r = t >> 3, c4 = (t & 7) << 2;
#pragma unroll
            for (int p = 0; p < 2; ++p) {
                int rr = r + p * 32;
                int g = row0 + rr;
                float4 v = make_float4(0.f, 0.f, 0.f, 0.f);
                if (g < N) v = *(const float4*)&X[(size_t)g * Dd + kc * 32 + c4];
                Xs[rr][c4] = v.x; Xs[rr][c4 + 1] = v.y;
                Xs[rr][c4 + 2] = v.z; Xs[rr][c4 + 3] = v.w;
            }
            // stage W tile: 32 k-rows x 128 cols
            int kr = t >> 5, cc = (t & 31) << 2;
#pragma unroll
            for (int p = 0; p < 4; ++p) {
                float4 v = *(const float4*)&W[(size_t)(kc * 32 + kr + p * 8) * Dd + cc];
                *(float4*)&Wl[kr + p * 8][cc] = v;
            }
        }
        __syncthreads();
#pragma unroll
        for (int kk = 0; kk < 32; ++kk) {
            float xv[4];
#pragma unroll
            for (int r = 0; r < 4; ++r) xv[r] = Xs[ty * 4 + r][kk];
            float4 w0 = *(float4*)&Wl[kk][c0];
            float4 w1 = *(float4*)&Wl[kk][c1];
#pragma unroll
            for (int r = 0; r < 4; ++r) {
                acc[r][0] += xv[r] * w0.x; acc[r][1] += xv[r] * w0.y;
                acc[r][2] += xv[r] * w0.z; acc[r][3] += xv[r] * w0.w;
                acc[r][4] += xv[r] * w1.x; acc[r][5] += xv[r] * w1.y;
                acc[r][6] += xv[r] * w1.z; acc[r][7] += xv[r] * w1.w;
            }
        }
        __syncthreads();
    }

    // epilogue: write h; reduce per-row dot with a_src/a_dst across the 16 col-lanes
#pragma unroll
    for (int r = 0; r < 4; ++r) {
        int g = row0 + ty * 4 + r;
        float ps = acc[r][0] * aS0.x + acc[r][1] * aS0.y + acc[r][2] * aS0.z + acc[r][3] * aS0.w
                 + acc[r][4] * aS1.x + acc[r][5] * aS1.y + acc[r][6] * aS1.z + acc[r][7] * aS1.w;
        float pd = acc[r][0] * aD0.x + acc[r][1] * aD0.y + acc[r][2] * aD0.z + acc[r][3] * aD0.w
                 + acc[r][4] * aD1.x + acc[r][5] * aD1.y + acc[r][6] * aD1.z + acc[r][7] * aD1.w;
#pragma unroll
        for (int o = 8; o; o >>= 1) { ps += __shfl_xor(ps, o); pd += __shfl_xor(pd, o); }
        if (g < N) {
            *(float4*)&H[(size_t)g * Dd + c0] = make_float4(acc[r][0], acc[r][1], acc[r][2], acc[r][3]);
            *(float4*)&H[(size_t)g * Dd + c1] = make_float4(acc[r][4], acc[r][5], acc[r][6], acc[r][7]);
            if (tx == 0) { hs[g] = ps; hd[g] = pd; }
        }
    }
}

// order-preserving float->uint encode for atomic max
__device__ __forceinline__ unsigned enc_f32(float f) {
    unsigned u = __float_as_uint(f);
    return (u & 0x80000000u) ? ~u : (u | 0x80000000u);
}
__device__ __forceinline__ float dec_f32(unsigned u) {
    return (u & 0x80000000u) ? __uint_as_float(u & 0x7fffffffu) : __uint_as_float(~u);
}

// ---------------- edge pass A: score + segment max ----------------
__global__ __launch_bounds__(256) void edge_max_kernel(
    const int* __restrict__ src, const int* __restrict__ dst,
    const float* __restrict__ hs, const float* __restrict__ hd,
    float* __restrict__ score, unsigned* __restrict__ m, int E, int Etot)
{
    for (int e = blockIdx.x * 256 + threadIdx.x; e < Etot; e += gridDim.x * 256) {
        int s_, d_;
        if (e < E) { s_ = src[e]; d_ = dst[e]; } else { s_ = d_ = e - E; }
        float sc = hs[s_] + hd[d_];
        sc = sc > 0.f ? sc : NEG_SLOPE * sc;
        score[e] = sc;
        atomicMax(&m[d_], enc_f32(sc));
    }
}

// ---------------- edge pass B: exp + segment sum ----------------
__global__ __launch_bounds__(256) void edge_sum_kernel(
    const int* __restrict__ dst, float* __restrict__ score,
    const unsigned* __restrict__ m, float* __restrict__ s, int E, int Etot)
{
    for (int e = blockIdx.x * 256 + threadIdx.x; e < Etot; e += gridDim.x * 256) {
        int d_ = (e < E) ? dst[e] : e - E;
        float mm = dec_f32(m[d_]);
        float ee = __expf(score[e] - mm);
        score[e] = ee;
        atomicAdd(&s[d_], ee);
    }
}

// ---------------- edge pass C: agg[dst] += ee * h[src] ----------------
// 32 threads per edge, float4 per thread.
__global__ __launch_bounds__(256) void edge_agg_kernel(
    const int* __restrict__ src, const int* __restrict__ dst,
    const float* __restrict__ score, const float* __restrict__ H,
    float* __restrict__ agg, int E, int Etot)
{
    long long gid = (long long)blockIdx.x * 256 + threadIdx.x;
    int e = (int)(gid >> 5);
    if (e >= Etot) return;
    int lane = (int)(gid & 31);
    int s_, d_;
    if (e < E) { s_ = src[e]; d_ = dst[e]; } else { s_ = d_ = e - E; }
    float w = score[e];
    const float4 hv = *(const float4*)&H[(size_t)s_ * Dd + lane * 4];
    float* ap = &agg[(size_t)d_ * Dd + lane * 4];
    atomicAdd(ap + 0, w * hv.x);
    atomicAdd(ap + 1, w * hv.y);
    atomicAdd(ap + 2, w * hv.z);
    atomicAdd(ap + 3, w * hv.w);
}

// ---------------- pointwise: out = relu(BN(agg/s + bias)) ----------------
__global__ __launch_bounds__(256) void bn_relu_kernel(
    const float* __restrict__ agg, const float* __restrict__ ssum,
    const float* __restrict__ bias, const float* __restrict__ gamma,
    const float* __restrict__ beta, const float* __restrict__ mean,
    const float* __restrict__ var, float* __restrict__ out, int N)
{
    int gid = blockIdx.x * 256 + threadIdx.x;
    int i = gid >> 5, l = gid & 31;
    if (i >= N) return;
    float inv = 1.0f / ssum[i];
    int d = l * 4;
    float4 a  = *(const float4*)&agg[(size_t)i * Dd + d];
    float4 b  = *(const float4*)&bias[d];
    float4 g  = *(const float4*)&gamma[d];
    float4 bt = *(const float4*)&beta[d];
    float4 mn = *(const float4*)&mean[d];
    float4 vr = *(const float4*)&var[d];
    float4 o;
    o.x = fmaxf((a.x * inv + b.x - mn.x) * (g.x * rsqrtf(vr.x + BN_EPS)) + bt.x, 0.f);
    o.y = fmaxf((a.y * inv + b.y - mn.y) * (g.y * rsqrtf(vr.y + BN_EPS)) + bt.y, 0.f);
    o.z = fmaxf((a.z * inv + b.z - mn.z) * (g.z * rsqrtf(vr.z + BN_EPS)) + bt.z, 0.f);
    o.w = fmaxf((a.w * inv + b.w - mn.w) * (g.w * rsqrtf(vr.w + BN_EPS)) + bt.w, 0.f);
    *(float4*)&out[(size_t)i * Dd + d] = o;
}

extern "C" void kernel_launch(void* const* d_in, const int* in_sizes, int n_in,
                              void* d_out, int out_size, void* d_ws, size_t ws_size,
                              hipStream_t stream)
{
    const float* x     = (const float*)d_in[0];
    const int*   ei    = (const int*)d_in[1];
    const float* Ws    = (const float*)d_in[2];
    const float* a_src = (const float*)d_in[3];
    const float* a_dst = (const float*)d_in[4];
    const float* bias  = (const float*)d_in[5];
    const float* gamma = (const float*)d_in[6];
    const float* beta  = (const float*)d_in[7];
    const float* mean  = (const float*)d_in[8];
    const float* var   = (const float*)d_in[9];
    float* out = (float*)d_out;
    float* ws  = (float*)d_ws;

    const int N = in_sizes[0] / Dd;
    const int E = in_sizes[1] / 2;
    const int Etot = E + N;
    const int* src = ei;
    const int* dst = ei + E;

    float* bufA  = ws;
    float* bufB  = ws + (size_t)N * Dd;
    float* hs    = bufB + (size_t)N * Dd;
    float* hd    = hs + N;
    float* mbuf  = hd + N;
    float* sbuf  = mbuf + N;
    float* score = sbuf + N;

    const int gemm_blocks = (N + 63) / 64;
    const int edge_blocks = (Etot + 255) / 256;
    const long long aggT  = (long long)Etot * 32;
    const int agg_blocks  = (int)((aggT + 255) / 256);
    const int pw_blocks   = (N * 32 + 255) / 256;

    for (int l = 0; l < 2; ++l) {
        const float* xin = (l == 0) ? x : bufA;
        float* h   = (l == 0) ? bufA : bufB;
        float* agg = (l == 0) ? bufB : bufA;
        float* xout = (l == 0) ? bufA : out;

        gemm_fused<<<gemm_blocks, 256, 0, stream>>>(
            xin, Ws + (size_t)l * Dd * Dd, a_src + l * Dd, a_dst + l * Dd, h, hs, hd, N);

        zero_kernel<<<(N * 32 + 255) / 256, 256, 0, stream>>>(agg, N * 32);
        zero_kernel<<<(2 * N / 4 + 255) / 256, 256, 0, stream>>>(mbuf, 2 * N / 4); // m and s adjacent

        edge_max_kernel<<<edge_blocks, 256, 0, stream>>>(src, dst, hs, hd, score, (unsigned*)mbuf, E, Etot);
        edge_sum_kernel<<<edge_blocks, 256, 0, stream>>>(dst, score, (const unsigned*)mbuf, sbuf, E, Etot);
        edge_agg_kernel<<<agg_blocks, 256, 0, stream>>>(src, dst, score, h, agg, E, Etot);

        bn_relu_kernel<<<pw_blocks, 256, 0, stream>>>(
            agg, sbuf, bias + l * Dd, gamma + l * Dd, beta + l * Dd,
            mean + l * Dd, var + l * Dd, xout, N);
    }
}

// Round 2
// 381.339 us; speedup vs baseline: 8.3463x; 8.3463x over previous
//
#include <hip/hip_runtime.h>

constexpr int Dd = 128;
constexpr float BN_EPS = 1e-12f;
constexpr float NEG_SLOPE = 0.2f;

// ---------------- fused GEMM: h = x@W, hs = h@a_src, hd = h@a_dst ----------------
__global__ __launch_bounds__(256) void gemm_fused(
    const float* __restrict__ X, const float* __restrict__ W,
    const float* __restrict__ asrc, const float* __restrict__ adst,
    float* __restrict__ H, float* __restrict__ hs, float* __restrict__ hd, int N)
{
    __shared__ float Xs[64][36];
    __shared__ float Wl[32][128];

    const int t  = threadIdx.x;
    const int tx = t & 15, ty = t >> 4;
    const int row0 = blockIdx.x * 64;
    const int c0 = tx * 4, c1 = 64 + tx * 4;

    const float4 aS0 = *(const float4*)&asrc[c0];
    const float4 aS1 = *(const float4*)&asrc[c1];
    const float4 aD0 = *(const float4*)&adst[c0];
    const float4 aD1 = *(const float4*)&adst[c1];

    float acc[4][8];
#pragma unroll
    for (int r = 0; r < 4; ++r)
#pragma unroll
        for (int c = 0; c < 8; ++c) acc[r][c] = 0.f;

    for (int kc = 0; kc < 4; ++kc) {
        {
            int r = t >> 3, c4 = (t & 7) << 2;
#pragma unroll
            for (int p = 0; p < 2; ++p) {
                int rr = r + p * 32;
                int g = row0 + rr;
                float4 v = make_float4(0.f, 0.f, 0.f, 0.f);
                if (g < N) v = *(const float4*)&X[(size_t)g * Dd + kc * 32 + c4];
                Xs[rr][c4] = v.x; Xs[rr][c4 + 1] = v.y;
                Xs[rr][c4 + 2] = v.z; Xs[rr][c4 + 3] = v.w;
            }
            int kr = t >> 5, cc = (t & 31) << 2;
#pragma unroll
            for (int p = 0; p < 4; ++p) {
                float4 v = *(const float4*)&W[(size_t)(kc * 32 + kr + p * 8) * Dd + cc];
                *(float4*)&Wl[kr + p * 8][cc] = v;
            }
        }
        __syncthreads();
#pragma unroll
        for (int kk = 0; kk < 32; ++kk) {
            float xv[4];
#pragma unroll
            for (int r = 0; r < 4; ++r) xv[r] = Xs[ty * 4 + r][kk];
            float4 w0 = *(float4*)&Wl[kk][c0];
            float4 w1 = *(float4*)&Wl[kk][c1];
#pragma unroll
            for (int r = 0; r < 4; ++r) {
                acc[r][0] += xv[r] * w0.x; acc[r][1] += xv[r] * w0.y;
                acc[r][2] += xv[r] * w0.z; acc[r][3] += xv[r] * w0.w;
                acc[r][4] += xv[r] * w1.x; acc[r][5] += xv[r] * w1.y;
                acc[r][6] += xv[r] * w1.z; acc[r][7] += xv[r] * w1.w;
            }
        }
        __syncthreads();
    }

#pragma unroll
    for (int r = 0; r < 4; ++r) {
        int g = row0 + ty * 4 + r;
        float ps = acc[r][0] * aS0.x + acc[r][1] * aS0.y + acc[r][2] * aS0.z + acc[r][3] * aS0.w
                 + acc[r][4] * aS1.x + acc[r][5] * aS1.y + acc[r][6] * aS1.z + acc[r][7] * aS1.w;
        float pd = acc[r][0] * aD0.x + acc[r][1] * aD0.y + acc[r][2] * aD0.z + acc[r][3] * aD0.w
                 + acc[r][4] * aD1.x + acc[r][5] * aD1.y + acc[r][6] * aD1.z + acc[r][7] * aD1.w;
#pragma unroll
        for (int o = 8; o; o >>= 1) { ps += __shfl_xor(ps, o); pd += __shfl_xor(pd, o); }
        if (g < N) {
            *(float4*)&H[(size_t)g * Dd + c0] = make_float4(acc[r][0], acc[r][1], acc[r][2], acc[r][3]);
            *(float4*)&H[(size_t)g * Dd + c1] = make_float4(acc[r][4], acc[r][5], acc[r][6], acc[r][7]);
            if (tx == 0) { hs[g] = ps; hd[g] = pd; }
        }
    }
}

// ---------------- CSR build ----------------
__global__ __launch_bounds__(256) void hist_kernel(
    const int* __restrict__ dst, int* __restrict__ cnt, int E)
{
    int e = blockIdx.x * 256 + threadIdx.x;
    if (e < E) atomicAdd(&cnt[dst[e]], 1);
}

// tile = 1024 counts per block; exclusive scan within tile + tile totals
__global__ __launch_bounds__(256) void scan1_kernel(
    const int* __restrict__ cnt, int* __restrict__ rowptr,
    int* __restrict__ partials, int N)
{
    __shared__ int lds[256];
    int t = threadIdx.x;
    int base = blockIdx.x * 1024 + t * 4;
    int c[4];
#pragma unroll
    for (int j = 0; j < 4; ++j) c[j] = (base + j < N) ? cnt[base + j] : 0;
    int tsum = c[0] + c[1] + c[2] + c[3];
    lds[t] = tsum;
    __syncthreads();
    for (int o = 1; o < 256; o <<= 1) {
        int v = (t >= o) ? lds[t - o] : 0;
        __syncthreads();
        lds[t] += v;
        __syncthreads();
    }
    int excl = lds[t] - tsum;
    int run = excl;
#pragma unroll
    for (int j = 0; j < 4; ++j) {
        if (base + j < N) rowptr[base + j] = run;
        run += c[j];
    }
    if (t == 255) partials[blockIdx.x] = lds[255];
}

__global__ __launch_bounds__(256) void scan2_kernel(int* __restrict__ partials, int nb)
{
    __shared__ int lds[256];
    int t = threadIdx.x;
    int v0 = (t < nb) ? partials[t] : 0;
    lds[t] = v0;
    __syncthreads();
    for (int o = 1; o < 256; o <<= 1) {
        int v = (t >= o) ? lds[t - o] : 0;
        __syncthreads();
        lds[t] += v;
        __syncthreads();
    }
    if (t < nb) partials[t] = lds[t] - v0;  // exclusive
}

__global__ __launch_bounds__(256) void scan3_kernel(
    int* __restrict__ rowptr, const int* __restrict__ partials, int N, int E)
{
    int i = blockIdx.x * 256 + threadIdx.x;
    if (i < N) rowptr[i] += partials[i >> 10];
    if (i == 0) rowptr[N] = E;
}

__global__ __launch_bounds__(256) void scatter_kernel(
    const int* __restrict__ src, const int* __restrict__ dst,
    const int* __restrict__ rowptr, int* __restrict__ cursor,
    int* __restrict__ ssrc, int E)
{
    int e = blockIdx.x * 256 + threadIdx.x;
    if (e >= E) return;
    int d = dst[e];
    int pos = rowptr[d] + atomicAdd(&cursor[d], 1);
    ssrc[pos] = src[e];
}

// ---------------- fused per-node GAT aggregation + BN + ReLU ----------------
// one wave (64 lanes) per destination node; online softmax over its edge list.
__global__ __launch_bounds__(256) void gat_agg_kernel(
    const int* __restrict__ rowptr, const int* __restrict__ ssrc,
    const float* __restrict__ hs, const float* __restrict__ hd,
    const float* __restrict__ H,
    const float* __restrict__ bias, const float* __restrict__ gamma,
    const float* __restrict__ beta, const float* __restrict__ mean,
    const float* __restrict__ var, float* __restrict__ out, int N)
{
    int wid = (blockIdx.x * 256 + threadIdx.x) >> 6;
    int lane = threadIdx.x & 63;
    if (wid >= N) return;
    const int i = wid;
    const float2* __restrict__ H2 = (const float2*)H;

    float hdi = hd[i];
    // self loop score (src=dst=i)
    float sc = hs[i] + hdi;
    sc = sc > 0.f ? sc : NEG_SLOPE * sc;
    float m = sc;          // running max
    float s = 1.f;         // exp(sc-m)=1
    float2 acc = H2[(size_t)i * 64 + lane];  // weight 1

    int rs = rowptr[i], re = rowptr[i + 1];
    for (int base = rs; base < re; base += 64) {
        int nv = re - base; if (nv > 64) nv = 64;
        int sj = (lane < nv) ? ssrc[base + lane] : 0;
        float scj = -1e30f;
        if (lane < nv) {
            float v = hs[sj] + hdi;
            scj = v > 0.f ? v : NEG_SLOPE * v;
        }
        float cm = scj;
#pragma unroll
        for (int o = 32; o; o >>= 1) cm = fmaxf(cm, __shfl_xor(cm, o));
        float nm = fmaxf(m, cm);
        float scale = __expf(m - nm);
        s *= scale; acc.x *= scale; acc.y *= scale;
        float ee = (lane < nv) ? __expf(scj - nm) : 0.f;
        float es = ee;
#pragma unroll
        for (int o = 32; o; o >>= 1) es += __shfl_xor(es, o);
        s += es;
        m = nm;
        for (int tt = 0; tt < nv; ++tt) {
            int st = __shfl(sj, tt);
            float et = __shfl(ee, tt);
            float2 hv = H2[(size_t)st * 64 + lane];
            acc.x += et * hv.x;
            acc.y += et * hv.y;
        }
    }

    float inv = 1.0f / s;
    const float2 b  = ((const float2*)bias)[lane];
    const float2 g  = ((const float2*)gamma)[lane];
    const float2 bt = ((const float2*)beta)[lane];
    const float2 mn = ((const float2*)mean)[lane];
    const float2 vr = ((const float2*)var)[lane];
    float2 o;
    o.x = fmaxf((acc.x * inv + b.x - mn.x) * (g.x * rsqrtf(vr.x + BN_EPS)) + bt.x, 0.f);
    o.y = fmaxf((acc.y * inv + b.y - mn.y) * (g.y * rsqrtf(vr.y + BN_EPS)) + bt.y, 0.f);
    ((float2*)out)[(size_t)i * 64 + lane] = o;
}

extern "C" void kernel_launch(void* const* d_in, const int* in_sizes, int n_in,
                              void* d_out, int out_size, void* d_ws, size_t ws_size,
                              hipStream_t stream)
{
    const float* x     = (const float*)d_in[0];
    const int*   ei    = (const int*)d_in[1];
    const float* Ws    = (const float*)d_in[2];
    const float* a_src = (const float*)d_in[3];
    const float* a_dst = (const float*)d_in[4];
    const float* bias  = (const float*)d_in[5];
    const float* gamma = (const float*)d_in[6];
    const float* beta  = (const float*)d_in[7];
    const float* mean  = (const float*)d_in[8];
    const float* var   = (const float*)d_in[9];
    float* out = (float*)d_out;
    float* ws  = (float*)d_ws;

    const int N = in_sizes[0] / Dd;
    const int E = in_sizes[1] / 2;
    const int* src = ei;
    const int* dst = ei + E;

    float* bufA = ws;
    float* bufB = bufA + (size_t)N * Dd;
    float* hs   = bufB + (size_t)N * Dd;
    float* hd   = hs + N;
    int* rowptr   = (int*)(hd + N);       // N+1
    int* cnt      = rowptr + (N + 1);     // N
    int* cursor   = cnt + N;              // N
    int* partials = cursor + N;           // up to 256
    int* ssrc     = partials + 256;       // E

    const int gemm_blocks = (N + 63) / 64;
    const int edge_blocks = (E + 255) / 256;
    const int scan_tiles  = (N + 1023) / 1024;
    const int node_blocks = (N + 255) / 256;
    const int agg_blocks  = (N * 64 + 255) / 256;

    // ---- CSR build (once; shared by both layers) ----
    hipMemsetAsync(cnt, 0, (size_t)2 * N * sizeof(int), stream);  // cnt + cursor
    hist_kernel<<<edge_blocks, 256, 0, stream>>>(dst, cnt, E);
    scan1_kernel<<<scan_tiles, 256, 0, stream>>>(cnt, rowptr, partials, N);
    scan2_kernel<<<1, 256, 0, stream>>>(partials, scan_tiles);
    scan3_kernel<<<node_blocks, 256, 0, stream>>>(rowptr, partials, N, E);
    scatter_kernel<<<edge_blocks, 256, 0, stream>>>(src, dst, rowptr, cursor, ssrc, E);

    for (int l = 0; l < 2; ++l) {
        const float* xin = (l == 0) ? x : bufB;
        float* h    = bufA;
        float* xout = (l == 0) ? bufB : out;

        gemm_fused<<<gemm_blocks, 256, 0, stream>>>(
            xin, Ws + (size_t)l * Dd * Dd, a_src + l * Dd, a_dst + l * Dd, h, hs, hd, N);

        gat_agg_kernel<<<agg_blocks, 256, 0, stream>>>(
            rowptr, ssrc, hs, hd, h,
            bias + l * Dd, gamma + l * Dd, beta + l * Dd,
            mean + l * Dd, var + l * Dd, xout, N);
    }
}

// Round 3
// 359.549 us; speedup vs baseline: 8.8521x; 1.0606x over previous
//
#include <hip/hip_runtime.h>

constexpr int Dd = 128;
constexpr float BN_EPS = 1e-12f;
constexpr float NEG_SLOPE = 0.2f;

using bf16x8 = __attribute__((ext_vector_type(8))) short;
using f32x4  = __attribute__((ext_vector_type(4))) float;

__device__ __forceinline__ ushort f2bf(float f) {
    unsigned u = __float_as_uint(f);
    return (ushort)((u + 0x7fffu + ((u >> 16) & 1u)) >> 16);
}

// ---------------- W transpose + bf16 prep: Wt[l][n][k] = bf16(W[l][k][n]) ----------------
__global__ __launch_bounds__(256) void wprep_kernel(const float* __restrict__ W, ushort* __restrict__ Wt)
{
    __shared__ float lds[32][33];
    const float* Wl = W + (size_t)blockIdx.x * Dd * Dd;
    ushort* Wo = Wt + (size_t)blockIdx.x * Dd * Dd;
    int t = threadIdx.x;
    int r = t >> 3, c4 = (t & 7) << 2;
    for (int tk = 0; tk < 4; ++tk)
    for (int tn = 0; tn < 4; ++tn) {
        int k0 = tk * 32, n0 = tn * 32;
        float4 v = *(const float4*)&Wl[(size_t)(k0 + r) * Dd + n0 + c4];
        lds[r][c4] = v.x; lds[r][c4 + 1] = v.y; lds[r][c4 + 2] = v.z; lds[r][c4 + 3] = v.w;
        __syncthreads();
        ushort4 o;
        o.x = f2bf(lds[c4 + 0][r]); o.y = f2bf(lds[c4 + 1][r]);
        o.z = f2bf(lds[c4 + 2][r]); o.w = f2bf(lds[c4 + 3][r]);
        *(ushort4*)&Wo[(size_t)(n0 + r) * Dd + k0 + c4] = o;
        __syncthreads();
    }
}

// ---------------- MFMA GEMM: Hb = bf16(x@W), hs = h@a_src, hd = h@a_dst ----------------
// 64 rows x 128 cols per block, 4 waves, K=128 in one LDS stage.
__global__ __launch_bounds__(256) void gemm_mfma(
    const float* __restrict__ X, const ushort* __restrict__ Wt,
    const float* __restrict__ asrc, const float* __restrict__ adst,
    ushort* __restrict__ Hb, float* __restrict__ hs, float* __restrict__ hd, int N)
{
    __shared__ ushort Xs[64 * 128];   // XOR-swizzled 16B blocks
    __shared__ ushort Bs[128 * 128];  // XOR-swizzled; row n holds Wt[n][k] (k contiguous)

    const int t = threadIdx.x;
    const int lane = t & 63, wid = t >> 6;
    const int row0 = blockIdx.x * 64;

    // stage X (fp32 -> bf16)
#pragma unroll
    for (int p = 0; p < 8; ++p) {
        int id = t + p * 256;
        int r = id >> 5, c4g = id & 31;
        int g = row0 + r;
        float4 v = make_float4(0.f, 0.f, 0.f, 0.f);
        if (g < N) v = *(const float4*)&X[(size_t)g * Dd + c4g * 4];
        ushort4 o; o.x = f2bf(v.x); o.y = f2bf(v.y); o.z = f2bf(v.z); o.w = f2bf(v.w);
        int b16 = c4g >> 1, sub = c4g & 1;
        *(ushort4*)&Xs[r * 128 + (((b16 ^ (r & 15)) << 3) | (sub << 2))] = o;
    }
    // stage Wt (already bf16)
#pragma unroll
    for (int p = 0; p < 8; ++p) {
        int id = t + p * 256;
        int n = id >> 4, b16 = id & 15;
        uint4 v = *(const uint4*)&Wt[(size_t)n * 128 + b16 * 8];
        *(uint4*)&Bs[n * 128 + ((b16 ^ (n & 15)) << 3)] = v;
    }
    __syncthreads();

    f32x4 acc[8];
#pragma unroll
    for (int f = 0; f < 8; ++f) acc[f] = (f32x4){0.f, 0.f, 0.f, 0.f};

#pragma unroll
    for (int kk = 0; kk < 4; ++kk) {
        int ra = wid * 16 + (lane & 15);
        int b16 = (lane >> 4) + kk * 4;
        bf16x8 a = *(bf16x8*)&Xs[ra * 128 + ((b16 ^ (ra & 15)) << 3)];
#pragma unroll
        for (int f = 0; f < 8; ++f) {
            int nb = f * 16 + (lane & 15);
            bf16x8 b = *(bf16x8*)&Bs[nb * 128 + ((b16 ^ (nb & 15)) << 3)];
            acc[f] = __builtin_amdgcn_mfma_f32_16x16x32_bf16(a, b, acc[f], 0, 0, 0);
        }
    }

    // epilogue: D layout col=lane&15 (+f*16), row=(lane>>4)*4+j
    float aS[8], aD[8];
#pragma unroll
    for (int f = 0; f < 8; ++f) {
        aS[f] = asrc[(lane & 15) + f * 16];
        aD[f] = adst[(lane & 15) + f * 16];
    }
#pragma unroll
    for (int j = 0; j < 4; ++j) {
        int r = row0 + wid * 16 + (lane >> 4) * 4 + j;
        float ps = 0.f, pd = 0.f;
#pragma unroll
        for (int f = 0; f < 8; ++f) { ps += acc[f][j] * aS[f]; pd += acc[f][j] * aD[f]; }
#pragma unroll
        for (int o = 8; o; o >>= 1) { ps += __shfl_xor(ps, o); pd += __shfl_xor(pd, o); }
        if (r < N) {
#pragma unroll
            for (int f = 0; f < 8; ++f)
                Hb[(size_t)r * Dd + (lane & 15) + f * 16] = f2bf(acc[f][j]);
            if ((lane & 15) == 0) { hs[r] = ps; hd[r] = pd; }
        }
    }
}

// ---------------- CSR build ----------------
__global__ __launch_bounds__(256) void hist_kernel(
    const int* __restrict__ dst, int* __restrict__ cnt, int E)
{
    int e = blockIdx.x * 256 + threadIdx.x;
    if (e < E) atomicAdd(&cnt[dst[e]], 1);
}

__global__ __launch_bounds__(256) void scan1_kernel(
    const int* __restrict__ cnt, int* __restrict__ rowptr,
    int* __restrict__ partials, int N)
{
    __shared__ int lds[256];
    int t = threadIdx.x;
    int base = blockIdx.x * 1024 + t * 4;
    int c[4];
#pragma unroll
    for (int j = 0; j < 4; ++j) c[j] = (base + j < N) ? cnt[base + j] : 0;
    int tsum = c[0] + c[1] + c[2] + c[3];
    lds[t] = tsum;
    __syncthreads();
    for (int o = 1; o < 256; o <<= 1) {
        int v = (t >= o) ? lds[t - o] : 0;
        __syncthreads();
        lds[t] += v;
        __syncthreads();
    }
    int run = lds[t] - tsum;
#pragma unroll
    for (int j = 0; j < 4; ++j) {
        if (base + j < N) rowptr[base + j] = run;
        run += c[j];
    }
    if (t == 255) partials[blockIdx.x] = lds[255];
}

__global__ __launch_bounds__(256) void scan2_kernel(int* __restrict__ partials, int nb)
{
    __shared__ int lds[256];
    int t = threadIdx.x;
    int v0 = (t < nb) ? partials[t] : 0;
    lds[t] = v0;
    __syncthreads();
    for (int o = 1; o < 256; o <<= 1) {
        int v = (t >= o) ? lds[t - o] : 0;
        __syncthreads();
        lds[t] += v;
        __syncthreads();
    }
    if (t < nb) partials[t] = lds[t] - v0;
}

__global__ __launch_bounds__(256) void scan3_kernel(
    int* __restrict__ rowptr, const int* __restrict__ partials,
    int* __restrict__ cursor, int N, int E)
{
    int i = blockIdx.x * 256 + threadIdx.x;
    if (i < N) {
        int v = rowptr[i] + partials[i >> 10];
        rowptr[i] = v;
        cursor[i] = v;
    }
    if (i == 0) rowptr[N] = E;
}

__global__ __launch_bounds__(256) void scatter_kernel(
    const int* __restrict__ src, const int* __restrict__ dst,
    int* __restrict__ cursor, int* __restrict__ ssrc, int E)
{
    int e = blockIdx.x * 256 + threadIdx.x;
    if (e >= E) return;
    int pos = atomicAdd(&cursor[dst[e]], 1);
    ssrc[pos] = src[e];
}

// ---------------- fused per-node GAT aggregation + BN + ReLU ----------------
// one wave per node; 4 edges in flight (16 lanes x 16B bf16 per row), 2-deep prefetch.
__global__ __launch_bounds__(256) void gat_agg_kernel(
    const int* __restrict__ rowptr, const int* __restrict__ ssrc,
    const float* __restrict__ hs, const float* __restrict__ hd,
    const ushort* __restrict__ Hb,
    const float* __restrict__ bias, const float* __restrict__ gamma,
    const float* __restrict__ beta, const float* __restrict__ mean,
    const float* __restrict__ var, float* __restrict__ out, int N)
{
    const int wid = (blockIdx.x * 256 + threadIdx.x) >> 6;
    if (wid >= N) return;
    const int lane = threadIdx.x & 63;
    const int q = lane >> 4, li = lane & 15;
    const int i = wid;
    const size_t rowO = (size_t)i * Dd;

    float hdi = hd[i];
    float sc = hs[i] + hdi;
    sc = sc > 0.f ? sc : NEG_SLOPE * sc;
    float m = sc, s = 1.f;   // self-loop: weight exp(0)=1

    float accv[8];
    {
        uint4 raw = *(const uint4*)&Hb[rowO + li * 8];
#pragma unroll
        for (int k = 0; k < 4; ++k) {
            unsigned w = ((const unsigned*)&raw)[k];
            accv[2 * k]     = (q == 0) ? __uint_as_float(w << 16) : 0.f;
            accv[2 * k + 1] = (q == 0) ? __uint_as_float(w & 0xffff0000u) : 0.f;
        }
    }

    const int rs = rowptr[i], re = rowptr[i + 1];
    for (int base = rs; base < re; base += 64) {
        int nv = re - base; if (nv > 64) nv = 64;
        int sj = (lane < nv) ? ssrc[base + lane] : 0;
        float scj = -1e30f;
        if (lane < nv) {
            float v = hs[sj] + hdi;
            scj = v > 0.f ? v : NEG_SLOPE * v;
        }
        float cm = scj;
#pragma unroll
        for (int o = 32; o; o >>= 1) cm = fmaxf(cm, __shfl_xor(cm, o));
        float nm = fmaxf(m, cm);
        float scale = __expf(m - nm);
        s *= scale;
#pragma unroll
        for (int k = 0; k < 8; ++k) accv[k] *= scale;
        float eej = (lane < nv) ? __expf(scj - nm) : 0.f;
        float es = eej;
#pragma unroll
        for (int o = 32; o; o >>= 1) es += __shfl_xor(es, o);
        s += es;
        m = nm;

        int idx0 = q < nv ? q : nv - 1;
        int st = __shfl(sj, idx0);
        uint4 cur = *(const uint4*)&Hb[(size_t)st * Dd + li * 8];
        for (int tt = 0; tt < nv; tt += 4) {
            int nxidx = tt + 4 + q; if (nxidx >= nv) nxidx = nv - 1;
            int stn = __shfl(sj, nxidx);
            uint4 nxt = cur;
            if (tt + 4 < nv) nxt = *(const uint4*)&Hb[(size_t)stn * Dd + li * 8];
            int eidx = tt + q;
            float et = __shfl(eej, eidx < nv ? eidx : nv - 1);
            if (eidx >= nv) et = 0.f;
#pragma unroll
            for (int k = 0; k < 4; ++k) {
                unsigned w = ((const unsigned*)&cur)[k];
                accv[2 * k]     += et * __uint_as_float(w << 16);
                accv[2 * k + 1] += et * __uint_as_float(w & 0xffff0000u);
            }
            cur = nxt;
        }
    }

#pragma unroll
    for (int k = 0; k < 8; ++k) {
        accv[k] += __shfl_xor(accv[k], 16);
        accv[k] += __shfl_xor(accv[k], 32);
    }

    if (q == 0) {
        float inv = 1.0f / s;
        int c0 = li * 8;
#pragma unroll
        for (int p = 0; p < 2; ++p) {
            float4 b  = *(const float4*)&bias[c0 + p * 4];
            float4 g  = *(const float4*)&gamma[c0 + p * 4];
            float4 bt = *(const float4*)&beta[c0 + p * 4];
            float4 mn = *(const float4*)&mean[c0 + p * 4];
            float4 vr = *(const float4*)&var[c0 + p * 4];
            float4 o;
            o.x = fmaxf((accv[p * 4 + 0] * inv + b.x - mn.x) * (g.x * rsqrtf(vr.x + BN_EPS)) + bt.x, 0.f);
            o.y = fmaxf((accv[p * 4 + 1] * inv + b.y - mn.y) * (g.y * rsqrtf(vr.y + BN_EPS)) + bt.y, 0.f);
            o.z = fmaxf((accv[p * 4 + 2] * inv + b.z - mn.z) * (g.z * rsqrtf(vr.z + BN_EPS)) + bt.z, 0.f);
            o.w = fmaxf((accv[p * 4 + 3] * inv + b.w - mn.w) * (g.w * rsqrtf(vr.w + BN_EPS)) + bt.w, 0.f);
            *(float4*)&out[rowO + c0 + p * 4] = o;
        }
    }
}

extern "C" void kernel_launch(void* const* d_in, const int* in_sizes, int n_in,
                              void* d_out, int out_size, void* d_ws, size_t ws_size,
                              hipStream_t stream)
{
    const float* x     = (const float*)d_in[0];
    const int*   ei    = (const int*)d_in[1];
    const float* Ws    = (const float*)d_in[2];
    const float* a_src = (const float*)d_in[3];
    const float* a_dst = (const float*)d_in[4];
    const float* bias  = (const float*)d_in[5];
    const float* gamma = (const float*)d_in[6];
    const float* beta  = (const float*)d_in[7];
    const float* mean  = (const float*)d_in[8];
    const float* var   = (const float*)d_in[9];
    float* out = (float*)d_out;
    float* ws  = (float*)d_ws;

    const int N = in_sizes[0] / Dd;
    const int E = in_sizes[1] / 2;
    const int* src = ei;
    const int* dst = ei + E;

    float* xmid = ws;                                   // N*128 f32 (layer-1 output)
    float* hs   = xmid + (size_t)N * Dd;                // N
    float* hd   = hs + N;                               // N
    ushort* Hb  = (ushort*)(hd + N);                    // N*128 bf16
    ushort* WtB = Hb + (size_t)N * Dd;                  // 2*128*128 bf16
    int* rowptr   = (int*)(WtB + 2 * Dd * Dd);          // N+1
    int* cnt      = rowptr + (N + 1);                   // N
    int* cursor   = cnt + N;                            // N
    int* partials = cursor + N;                         // 256
    int* ssrc     = partials + 256;                     // E

    const int gemm_blocks = (N + 63) / 64;
    const int edge_blocks = (E + 255) / 256;
    const int scan_tiles  = (N + 1023) / 1024;
    const int node_blocks = (N + 255) / 256;
    const int agg_blocks  = (N * 64 + 255) / 256;

    // prep + CSR build (shared by both layers)
    wprep_kernel<<<2, 256, 0, stream>>>(Ws, WtB);
    hipMemsetAsync(cnt, 0, (size_t)N * sizeof(int), stream);
    hist_kernel<<<edge_blocks, 256, 0, stream>>>(dst, cnt, E);
    scan1_kernel<<<scan_tiles, 256, 0, stream>>>(cnt, rowptr, partials, N);
    scan2_kernel<<<1, 256, 0, stream>>>(partials, scan_tiles);
    scan3_kernel<<<node_blocks, 256, 0, stream>>>(rowptr, partials, cursor, N, E);
    scatter_kernel<<<edge_blocks, 256, 0, stream>>>(src, dst, cursor, ssrc, E);

    for (int l = 0; l < 2; ++l) {
        const float* xin = (l == 0) ? x : xmid;
        float* xout = (l == 0) ? xmid : out;

        gemm_mfma<<<gemm_blocks, 256, 0, stream>>>(
            xin, WtB + (size_t)l * Dd * Dd, a_src + l * Dd, a_dst + l * Dd, Hb, hs, hd, N);

        gat_agg_kernel<<<agg_blocks, 256, 0, stream>>>(
            rowptr, ssrc, hs, hd, Hb,
            bias + l * Dd, gamma + l * Dd, beta + l * Dd,
            mean + l * Dd, var + l * Dd, xout, N);
    }
}

// Round 4
// 300.370 us; speedup vs baseline: 10.5962x; 1.1970x over previous
//
#include <hip/hip_runtime.h>

constexpr int Dd = 128;
constexpr float BN_EPS = 1e-12f;
constexpr float NEG_SLOPE = 0.2f;

using bf16x8 = __attribute__((ext_vector_type(8))) short;
using f32x4  = __attribute__((ext_vector_type(4))) float;

__device__ __forceinline__ ushort f2bf(float f) {
    unsigned u = __float_as_uint(f);
    return (ushort)((u + 0x7fffu + ((u >> 16) & 1u)) >> 16);
}

// ---------------- W transpose + bf16 prep + cnt zero ----------------
// blocks 0..1: Wt[l][n][k] = bf16(W[l][k][n]); blocks 2..: zero cnt
__global__ __launch_bounds__(256) void wprep_zero_kernel(
    const float* __restrict__ W, ushort* __restrict__ Wt,
    int* __restrict__ cnt, int N)
{
    int t = threadIdx.x;
    if (blockIdx.x >= 2) {
        int i = (blockIdx.x - 2) * 1024 + t * 4;
#pragma unroll
        for (int j = 0; j < 4; ++j)
            if (i + j < N) cnt[i + j] = 0;
        return;
    }
    __shared__ float lds[32][33];
    const float* Wl = W + (size_t)blockIdx.x * Dd * Dd;
    ushort* Wo = Wt + (size_t)blockIdx.x * Dd * Dd;
    int r = t >> 3, c4 = (t & 7) << 2;
    for (int tk = 0; tk < 4; ++tk)
    for (int tn = 0; tn < 4; ++tn) {
        int k0 = tk * 32, n0 = tn * 32;
        float4 v = *(const float4*)&Wl[(size_t)(k0 + r) * Dd + n0 + c4];
        lds[r][c4] = v.x; lds[r][c4 + 1] = v.y; lds[r][c4 + 2] = v.z; lds[r][c4 + 3] = v.w;
        __syncthreads();
        ushort4 o;
        o.x = f2bf(lds[c4 + 0][r]); o.y = f2bf(lds[c4 + 1][r]);
        o.z = f2bf(lds[c4 + 2][r]); o.w = f2bf(lds[c4 + 3][r]);
        *(ushort4*)&Wo[(size_t)(n0 + r) * Dd + k0 + c4] = o;
        __syncthreads();
    }
}

// ---------------- MFMA GEMM: Hb = bf16(x@W), hs = h@a_src, hd = h@a_dst ----------------
template<bool BF16IN>
__global__ __launch_bounds__(256) void gemm_mfma(
    const void* __restrict__ Xv, const ushort* __restrict__ Wt,
    const float* __restrict__ asrc, const float* __restrict__ adst,
    ushort* __restrict__ Hb, float* __restrict__ hs, float* __restrict__ hd, int N)
{
    __shared__ ushort Xs[64 * 128];   // XOR-swizzled 16B blocks
    __shared__ ushort Bs[128 * 128];

    const int t = threadIdx.x;
    const int lane = t & 63, wid = t >> 6;
    const int row0 = blockIdx.x * 64;

    if constexpr (BF16IN) {
        const ushort* X = (const ushort*)Xv;
#pragma unroll
        for (int p = 0; p < 4; ++p) {
            int id = t + p * 256;
            int r = id >> 4, b16 = id & 15;
            int g = row0 + r;
            uint4 v = make_uint4(0, 0, 0, 0);
            if (g < N) v = *(const uint4*)&X[(size_t)g * Dd + b16 * 8];
            *(uint4*)&Xs[r * 128 + ((b16 ^ (r & 15)) << 3)] = v;
        }
    } else {
        const float* X = (const float*)Xv;
#pragma unroll
        for (int p = 0; p < 8; ++p) {
            int id = t + p * 256;
            int r = id >> 5, c4g = id & 31;
            int g = row0 + r;
            float4 v = make_float4(0.f, 0.f, 0.f, 0.f);
            if (g < N) v = *(const float4*)&X[(size_t)g * Dd + c4g * 4];
            ushort4 o; o.x = f2bf(v.x); o.y = f2bf(v.y); o.z = f2bf(v.z); o.w = f2bf(v.w);
            int b16 = c4g >> 1, sub = c4g & 1;
            *(ushort4*)&Xs[r * 128 + (((b16 ^ (r & 15)) << 3) | (sub << 2))] = o;
        }
    }
#pragma unroll
    for (int p = 0; p < 8; ++p) {
        int id = t + p * 256;
        int n = id >> 4, b16 = id & 15;
        uint4 v = *(const uint4*)&Wt[(size_t)n * 128 + b16 * 8];
        *(uint4*)&Bs[n * 128 + ((b16 ^ (n & 15)) << 3)] = v;
    }
    __syncthreads();

    f32x4 acc[8];
#pragma unroll
    for (int f = 0; f < 8; ++f) acc[f] = (f32x4){0.f, 0.f, 0.f, 0.f};

#pragma unroll
    for (int kk = 0; kk < 4; ++kk) {
        int ra = wid * 16 + (lane & 15);
        int b16 = (lane >> 4) + kk * 4;
        bf16x8 a = *(bf16x8*)&Xs[ra * 128 + ((b16 ^ (ra & 15)) << 3)];
#pragma unroll
        for (int f = 0; f < 8; ++f) {
            int nb = f * 16 + (lane & 15);
            bf16x8 b = *(bf16x8*)&Bs[nb * 128 + ((b16 ^ (nb & 15)) << 3)];
            acc[f] = __builtin_amdgcn_mfma_f32_16x16x32_bf16(a, b, acc[f], 0, 0, 0);
        }
    }

    float aS[8], aD[8];
#pragma unroll
    for (int f = 0; f < 8; ++f) {
        aS[f] = asrc[(lane & 15) + f * 16];
        aD[f] = adst[(lane & 15) + f * 16];
    }
#pragma unroll
    for (int j = 0; j < 4; ++j) {
        int r = row0 + wid * 16 + (lane >> 4) * 4 + j;
        float ps = 0.f, pd = 0.f;
#pragma unroll
        for (int f = 0; f < 8; ++f) { ps += acc[f][j] * aS[f]; pd += acc[f][j] * aD[f]; }
#pragma unroll
        for (int o = 8; o; o >>= 1) { ps += __shfl_xor(ps, o); pd += __shfl_xor(pd, o); }
        if (r < N) {
#pragma unroll
            for (int f = 0; f < 8; ++f)
                Hb[(size_t)r * Dd + (lane & 15) + f * 16] = f2bf(acc[f][j]);
            if ((lane & 15) == 0) { hs[r] = ps; hd[r] = pd; }
        }
    }
}

// ---------------- CSR build ----------------
__global__ __launch_bounds__(256) void hist_kernel(
    const int* __restrict__ dst, int* __restrict__ cnt, int E)
{
    int e = blockIdx.x * 256 + threadIdx.x;
    if (e < E) atomicAdd(&cnt[dst[e]], 1);
}

__global__ __launch_bounds__(256) void scan1_kernel(
    const int* __restrict__ cnt, int* __restrict__ rowptr,
    int* __restrict__ partials, int N)
{
    __shared__ int lds[256];
    int t = threadIdx.x;
    int base = blockIdx.x * 1024 + t * 4;
    int c[4];
#pragma unroll
    for (int j = 0; j < 4; ++j) c[j] = (base + j < N) ? cnt[base + j] : 0;
    int tsum = c[0] + c[1] + c[2] + c[3];
    lds[t] = tsum;
    __syncthreads();
    for (int o = 1; o < 256; o <<= 1) {
        int v = (t >= o) ? lds[t - o] : 0;
        __syncthreads();
        lds[t] += v;
        __syncthreads();
    }
    int run = lds[t] - tsum;
#pragma unroll
    for (int j = 0; j < 4; ++j) {
        if (base + j < N) rowptr[base + j] = run;
        run += c[j];
    }
    if (t == 255) partials[blockIdx.x] = lds[255];
}

__global__ __launch_bounds__(256) void scan2_kernel(int* __restrict__ partials, int nb)
{
    __shared__ int lds[256];
    int t = threadIdx.x;
    int v0 = (t < nb) ? partials[t] : 0;
    lds[t] = v0;
    __syncthreads();
    for (int o = 1; o < 256; o <<= 1) {
        int v = (t >= o) ? lds[t - o] : 0;
        __syncthreads();
        lds[t] += v;
        __syncthreads();
    }
    if (t < nb) partials[t] = lds[t] - v0;
}

__global__ __launch_bounds__(256) void scan3_kernel(
    int* __restrict__ rowptr, const int* __restrict__ partials,
    int* __restrict__ cursor, int N, int E)
{
    int i = blockIdx.x * 256 + threadIdx.x;
    if (i < N) {
        int v = rowptr[i] + partials[i >> 10];
        rowptr[i] = v;
        cursor[i] = v;
    }
    if (i == 0) rowptr[N] = E;
}

__global__ __launch_bounds__(256) void scatter_kernel(
    const int* __restrict__ src, const int* __restrict__ dst,
    int* __restrict__ cursor, int* __restrict__ ssrc, int E)
{
    int e = blockIdx.x * 256 + threadIdx.x;
    if (e >= E) return;
    int pos = atomicAdd(&cursor[dst[e]], 1);
    ssrc[pos] = src[e];
}

// ---------------- fused per-node GAT aggregation + BN + ReLU ----------------
// one wave per node; each quarter-wave (16 lanes) owns edge stream pos=it*4+q.
// no max-subtraction (scores bounded, fp32 exp safe) -> shuffle-free inner loop.
template<bool BF16OUT>
__global__ __launch_bounds__(256) void gat_agg_kernel(
    const int* __restrict__ rowptr, const int* __restrict__ ssrc,
    const float* __restrict__ hs, const float* __restrict__ hd,
    const ushort* __restrict__ Hb,
    const float* __restrict__ bias, const float* __restrict__ gamma,
    const float* __restrict__ beta, const float* __restrict__ mean,
    const float* __restrict__ var, void* __restrict__ outv, int N)
{
    const int wid = (blockIdx.x * 256 + threadIdx.x) >> 6;
    if (wid >= N) return;
    const int lane = threadIdx.x & 63;
    const int q = lane >> 4, li = lane & 15;
    const size_t rowO = (size_t)wid * Dd;

    const float hdi = hd[wid];
    float sc0 = hs[wid] + hdi;
    sc0 = sc0 > 0.f ? sc0 : NEG_SLOPE * sc0;
    const float w0 = (q == 0) ? __expf(sc0) : 0.f;

    float acc[8];
    float s = w0;
    {
        uint4 own = *(const uint4*)&Hb[rowO + li * 8];
#pragma unroll
        for (int k = 0; k < 4; ++k) {
            unsigned w = ((const unsigned*)&own)[k];
            acc[2 * k]     = w0 * __uint_as_float(w << 16);
            acc[2 * k + 1] = w0 * __uint_as_float(w & 0xffff0000u);
        }
    }

    const int rs = rowptr[wid];
    const int nv = rowptr[wid + 1] - rs;

    // depth-2 predicated prefetch pipeline
    uint4 r0 = make_uint4(0, 0, 0, 0), r1 = make_uint4(0, 0, 0, 0);
    float h0 = 0.f, h1 = 0.f;
    if (q < nv) {
        int sj = ssrc[rs + q];
        h0 = hs[sj];
        r0 = *(const uint4*)&Hb[(size_t)sj * Dd + li * 8];
    }
    if (4 + q < nv) {
        int sj = ssrc[rs + 4 + q];
        h1 = hs[sj];
        r1 = *(const uint4*)&Hb[(size_t)sj * Dd + li * 8];
    }

    const int nit = (nv + 3) >> 2;
    for (int it = 0; it < nit; ++it) {
        float scv = h0 + hdi;
        scv = scv > 0.f ? scv : NEG_SLOPE * scv;
        float ee = (it * 4 + q < nv) ? __expf(scv) : 0.f;
        s += ee;
        uint4 rc = r0;
        r0 = r1; h0 = h1;
        int pn = (it + 2) * 4 + q;
        if (pn < nv) {
            int sj = ssrc[rs + pn];
            h1 = hs[sj];
            r1 = *(const uint4*)&Hb[(size_t)sj * Dd + li * 8];
        }
#pragma unroll
        for (int k = 0; k < 4; ++k) {
            unsigned w = ((const unsigned*)&rc)[k];
            acc[2 * k]     += ee * __uint_as_float(w << 16);
            acc[2 * k + 1] += ee * __uint_as_float(w & 0xffff0000u);
        }
    }

    // cross-quarter reduce (values uniform within each quarter)
#pragma unroll
    for (int k = 0; k < 8; ++k) {
        acc[k] += __shfl_xor(acc[k], 16);
        acc[k] += __shfl_xor(acc[k], 32);
    }
    s += __shfl_xor(s, 16);
    s += __shfl_xor(s, 32);

    if (q == 0) {
        float inv = 1.0f / s;
        int c0 = li * 8;
        float o[8];
#pragma unroll
        for (int m = 0; m < 8; ++m) {
            float bm = bias[c0 + m], gm = gamma[c0 + m], btm = beta[c0 + m];
            float mnm = mean[c0 + m], vrm = var[c0 + m];
            o[m] = fmaxf((acc[m] * inv + bm - mnm) * (gm * rsqrtf(vrm + BN_EPS)) + btm, 0.f);
        }
        if constexpr (BF16OUT) {
            ushort* out = (ushort*)outv;
            uint4 pk;
#pragma unroll
            for (int k = 0; k < 4; ++k)
                ((unsigned*)&pk)[k] = (unsigned)f2bf(o[2 * k]) | ((unsigned)f2bf(o[2 * k + 1]) << 16);
            *(uint4*)&out[rowO + c0] = pk;
        } else {
            float* out = (float*)outv;
            *(float4*)&out[rowO + c0]     = make_float4(o[0], o[1], o[2], o[3]);
            *(float4*)&out[rowO + c0 + 4] = make_float4(o[4], o[5], o[6], o[7]);
        }
    }
}

extern "C" void kernel_launch(void* const* d_in, const int* in_sizes, int n_in,
                              void* d_out, int out_size, void* d_ws, size_t ws_size,
                              hipStream_t stream)
{
    const float* x     = (const float*)d_in[0];
    const int*   ei    = (const int*)d_in[1];
    const float* Ws    = (const float*)d_in[2];
    const float* a_src = (const float*)d_in[3];
    const float* a_dst = (const float*)d_in[4];
    const float* bias  = (const float*)d_in[5];
    const float* gamma = (const float*)d_in[6];
    const float* beta  = (const float*)d_in[7];
    const float* mean  = (const float*)d_in[8];
    const float* var   = (const float*)d_in[9];
    float* out = (float*)d_out;
    float* ws  = (float*)d_ws;

    const int N = in_sizes[0] / Dd;
    const int E = in_sizes[1] / 2;
    const int* src = ei;
    const int* dst = ei + E;

    float* hs    = ws;                                  // N
    float* hd    = hs + N;                              // N
    ushort* Hb   = (ushort*)(hd + N);                   // N*128 bf16
    ushort* xmid = Hb + (size_t)N * Dd;                 // N*128 bf16 (layer-0 out)
    ushort* WtB  = xmid + (size_t)N * Dd;               // 2*128*128 bf16
    int* rowptr   = (int*)(WtB + 2 * Dd * Dd);          // N+1
    int* cnt      = rowptr + (N + 1);                   // N
    int* cursor   = cnt + N;                            // N
    int* partials = cursor + N;                         // 256
    int* ssrc     = partials + 256;                     // E

    const int gemm_blocks = (N + 63) / 64;
    const int edge_blocks = (E + 255) / 256;
    const int scan_tiles  = (N + 1023) / 1024;
    const int node_blocks = (N + 255) / 256;
    const int agg_blocks  = (N * 64 + 255) / 256;

    // prep + CSR build (shared by both layers)
    wprep_zero_kernel<<<2 + scan_tiles, 256, 0, stream>>>(Ws, WtB, cnt, N);
    hist_kernel<<<edge_blocks, 256, 0, stream>>>(dst, cnt, E);
    scan1_kernel<<<scan_tiles, 256, 0, stream>>>(cnt, rowptr, partials, N);
    scan2_kernel<<<1, 256, 0, stream>>>(partials, scan_tiles);
    scan3_kernel<<<node_blocks, 256, 0, stream>>>(rowptr, partials, cursor, N, E);
    scatter_kernel<<<edge_blocks, 256, 0, stream>>>(src, dst, cursor, ssrc, E);

    // layer 0: f32 in -> bf16 xmid
    gemm_mfma<false><<<gemm_blocks, 256, 0, stream>>>(
        x, WtB, a_src, a_dst, Hb, hs, hd, N);
    gat_agg_kernel<true><<<agg_blocks, 256, 0, stream>>>(
        rowptr, ssrc, hs, hd, Hb, bias, gamma, beta, mean, var, (void*)xmid, N);

    // layer 1: bf16 in -> f32 out
    gemm_mfma<true><<<gemm_blocks, 256, 0, stream>>>(
        xmid, WtB + (size_t)Dd * Dd, a_src + Dd, a_dst + Dd, Hb, hs, hd, N);
    gat_agg_kernel<false><<<agg_blocks, 256, 0, stream>>>(
        rowptr, ssrc, hs, hd, Hb, bias + Dd, gamma + Dd, beta + Dd,
        mean + Dd, var + Dd, (void*)out, N);
}

// Round 5
// 253.326 us; speedup vs baseline: 12.5640x; 1.1857x over previous
//
#include <hip/hip_runtime.h>

constexpr int Dd = 128;
constexpr float BN_EPS = 1e-12f;
constexpr float NEG_SLOPE = 0.2f;

using bf16x8 = __attribute__((ext_vector_type(8))) short;
using f32x4  = __attribute__((ext_vector_type(4))) float;

__device__ __forceinline__ ushort f2bf(float f) {
    unsigned u = __float_as_uint(f);
    return (ushort)((u + 0x7fffu + ((u >> 16) & 1u)) >> 16);
}

// ---------------- W transpose + bf16 prep + coarse-cnt zero ----------------
__global__ __launch_bounds__(256) void wprep_zero_kernel(
    const float* __restrict__ W, ushort* __restrict__ Wt, int* __restrict__ cntc)
{
    int t = threadIdx.x;
    if (blockIdx.x >= 2) {           // block 2: zero coarse counters
        cntc[t] = 0;
        return;
    }
    __shared__ float lds[32][33];
    const float* Wl = W + (size_t)blockIdx.x * Dd * Dd;
    ushort* Wo = Wt + (size_t)blockIdx.x * Dd * Dd;
    int r = t >> 3, c4 = (t & 7) << 2;
    for (int tk = 0; tk < 4; ++tk)
    for (int tn = 0; tn < 4; ++tn) {
        int k0 = tk * 32, n0 = tn * 32;
        float4 v = *(const float4*)&Wl[(size_t)(k0 + r) * Dd + n0 + c4];
        lds[r][c4] = v.x; lds[r][c4 + 1] = v.y; lds[r][c4 + 2] = v.z; lds[r][c4 + 3] = v.w;
        __syncthreads();
        ushort4 o;
        o.x = f2bf(lds[c4 + 0][r]); o.y = f2bf(lds[c4 + 1][r]);
        o.z = f2bf(lds[c4 + 2][r]); o.w = f2bf(lds[c4 + 3][r]);
        *(ushort4*)&Wo[(size_t)(n0 + r) * Dd + k0 + c4] = o;
        __syncthreads();
    }
}

// ---------------- coarse hist (LDS-aggregated) ----------------
__global__ __launch_bounds__(256) void coarse_hist_kernel(
    const int* __restrict__ dst, int* __restrict__ cntc, int E, int NB)
{
    __shared__ int lh[256];
    int t = threadIdx.x;
    lh[t] = 0;
    __syncthreads();
    for (int e = blockIdx.x * 256 + t; e < E; e += gridDim.x * 256)
        atomicAdd(&lh[dst[e] >> 8], 1);
    __syncthreads();
    if (t < NB && lh[t]) atomicAdd(&cntc[t], lh[t]);
}

// ---------------- coarse scan (1 block) ----------------
__global__ __launch_bounds__(256) void coarse_scan_kernel(
    const int* __restrict__ cntc, int* __restrict__ base,
    int* __restrict__ cursor, int NB, int E)
{
    __shared__ int lds[256];
    int t = threadIdx.x;
    int v0 = (t < NB) ? cntc[t] : 0;
    lds[t] = v0;
    __syncthreads();
    for (int o = 1; o < 256; o <<= 1) {
        int v = (t >= o) ? lds[t - o] : 0;
        __syncthreads();
        lds[t] += v;
        __syncthreads();
    }
    int excl = lds[t] - v0;
    if (t < NB) { base[t] = excl; cursor[t] = excl; }
    if (t == 0) base[NB] = E;
}

// ---------------- partition: stage by bucket in LDS, coalesced flush ----------------
// chunk = 4096 edges/block; packed = src | dst_lo<<16 | bucket<<24  (N < 65536)
__global__ __launch_bounds__(256) void partition_kernel(
    const int* __restrict__ src, const int* __restrict__ dst,
    int* __restrict__ cursor, unsigned* __restrict__ gpart, int E)
{
    __shared__ int h[256], lb[256], gs[256], cur[256];
    __shared__ unsigned staged[4096];
    const int t = threadIdx.x;
    const int c0 = blockIdx.x * 4096;
    const int count = min(4096, E - c0);

    h[t] = 0; cur[t] = 0;
    __syncthreads();
#pragma unroll
    for (int j = 0; j < 16; ++j) {
        int idx = j * 256 + t;
        if (idx < count) atomicAdd(&h[dst[c0 + idx] >> 8], 1);
    }
    __syncthreads();
    // scan h -> lb (exclusive)
    {
        int v0 = h[t];
        lb[t] = v0;
        __syncthreads();
        for (int o = 1; o < 256; o <<= 1) {
            int v = (t >= o) ? lb[t - o] : 0;
            __syncthreads();
            lb[t] += v;
            __syncthreads();
        }
        lb[t] -= v0;
    }
    if (h[t]) gs[t] = atomicAdd(&cursor[t], h[t]);
    __syncthreads();
#pragma unroll
    for (int j = 0; j < 16; ++j) {
        int idx = j * 256 + t;
        if (idx < count) {
            int d = dst[c0 + idx], s = src[c0 + idx];
            int b = d >> 8;
            int pos = lb[b] + atomicAdd(&cur[b], 1);
            staged[pos] = (unsigned)s | ((unsigned)(d & 255) << 16) | ((unsigned)b << 24);
        }
    }
    __syncthreads();
#pragma unroll
    for (int j = 0; j < 16; ++j) {
        int idx = j * 256 + t;
        if (idx < count) {
            unsigned p = staged[idx];
            int b = p >> 24;
            gpart[gs[b] + (idx - lb[b])] = p;
        }
    }
}

// ---------------- per-bucket CSR finalize: rowptr + ordered ssrc ----------------
__global__ __launch_bounds__(256) void bucket_csr_kernel(
    const unsigned* __restrict__ gpart, const int* __restrict__ base,
    int* __restrict__ rowptr, int* __restrict__ ssrc, int N, int NB, int E)
{
    __shared__ int h[256], lb[256], cur[256];
    const int t = threadIdx.x;
    const int b = blockIdx.x;
    const int cb = base[b], ce = base[b + 1];
    const int cnt = ce - cb;

    h[t] = 0; cur[t] = 0;
    __syncthreads();
    for (int o = t; o < cnt; o += 256)
        atomicAdd(&h[(gpart[cb + o] >> 16) & 255], 1);
    __syncthreads();
    {
        int v0 = h[t];
        lb[t] = v0;
        __syncthreads();
        for (int o = 1; o < 256; o <<= 1) {
            int v = (t >= o) ? lb[t - o] : 0;
            __syncthreads();
            lb[t] += v;
            __syncthreads();
        }
        lb[t] -= v0;
    }
    int n0 = b * 256 + t;
    if (n0 < N) rowptr[n0] = cb + lb[t];
    if (b == 0 && t == 0) rowptr[N] = E;
    __syncthreads();
    for (int o = t; o < cnt; o += 256) {
        unsigned p = gpart[cb + o];
        int n = (p >> 16) & 255;
        int pos = lb[n] + atomicAdd(&cur[n], 1);
        ssrc[cb + pos] = (int)(p & 0xFFFFu);
    }
}

// ---------------- MFMA GEMM: Hb = bf16(x@W), hs = h@a_src, hd = h@a_dst ----------------
template<bool BF16IN>
__global__ __launch_bounds__(256) void gemm_mfma(
    const void* __restrict__ Xv, const ushort* __restrict__ Wt,
    const float* __restrict__ asrc, const float* __restrict__ adst,
    ushort* __restrict__ Hb, float* __restrict__ hs, float* __restrict__ hd, int N)
{
    __shared__ ushort Xs[64 * 128];
    __shared__ ushort Bs[128 * 128];

    const int t = threadIdx.x;
    const int lane = t & 63, wid = t >> 6;
    const int row0 = blockIdx.x * 64;

    if constexpr (BF16IN) {
        const ushort* X = (const ushort*)Xv;
#pragma unroll
        for (int p = 0; p < 4; ++p) {
            int id = t + p * 256;
            int r = id >> 4, b16 = id & 15;
            int g = row0 + r;
            uint4 v = make_uint4(0, 0, 0, 0);
            if (g < N) v = *(const uint4*)&X[(size_t)g * Dd + b16 * 8];
            *(uint4*)&Xs[r * 128 + ((b16 ^ (r & 15)) << 3)] = v;
        }
    } else {
        const float* X = (const float*)Xv;
#pragma unroll
        for (int p = 0; p < 8; ++p) {
            int id = t + p * 256;
            int r = id >> 5, c4g = id & 31;
            int g = row0 + r;
            float4 v = make_float4(0.f, 0.f, 0.f, 0.f);
            if (g < N) v = *(const float4*)&X[(size_t)g * Dd + c4g * 4];
            ushort4 o; o.x = f2bf(v.x); o.y = f2bf(v.y); o.z = f2bf(v.z); o.w = f2bf(v.w);
            int b16 = c4g >> 1, sub = c4g & 1;
            *(ushort4*)&Xs[r * 128 + (((b16 ^ (r & 15)) << 3) | (sub << 2))] = o;
        }
    }
#pragma unroll
    for (int p = 0; p < 8; ++p) {
        int id = t + p * 256;
        int n = id >> 4, b16 = id & 15;
        uint4 v = *(const uint4*)&Wt[(size_t)n * 128 + b16 * 8];
        *(uint4*)&Bs[n * 128 + ((b16 ^ (n & 15)) << 3)] = v;
    }
    __syncthreads();

    f32x4 acc[8];
#pragma unroll
    for (int f = 0; f < 8; ++f) acc[f] = (f32x4){0.f, 0.f, 0.f, 0.f};

#pragma unroll
    for (int kk = 0; kk < 4; ++kk) {
        int ra = wid * 16 + (lane & 15);
        int b16 = (lane >> 4) + kk * 4;
        bf16x8 a = *(bf16x8*)&Xs[ra * 128 + ((b16 ^ (ra & 15)) << 3)];
#pragma unroll
        for (int f = 0; f < 8; ++f) {
            int nb = f * 16 + (lane & 15);
            bf16x8 b = *(bf16x8*)&Bs[nb * 128 + ((b16 ^ (nb & 15)) << 3)];
            acc[f] = __builtin_amdgcn_mfma_f32_16x16x32_bf16(a, b, acc[f], 0, 0, 0);
        }
    }

    float aS[8], aD[8];
#pragma unroll
    for (int f = 0; f < 8; ++f) {
        aS[f] = asrc[(lane & 15) + f * 16];
        aD[f] = adst[(lane & 15) + f * 16];
    }
#pragma unroll
    for (int j = 0; j < 4; ++j) {
        int r = row0 + wid * 16 + (lane >> 4) * 4 + j;
        float ps = 0.f, pd = 0.f;
#pragma unroll
        for (int f = 0; f < 8; ++f) { ps += acc[f][j] * aS[f]; pd += acc[f][j] * aD[f]; }
#pragma unroll
        for (int o = 8; o; o >>= 1) { ps += __shfl_xor(ps, o); pd += __shfl_xor(pd, o); }
        if (r < N) {
#pragma unroll
            for (int f = 0; f < 8; ++f)
                Hb[(size_t)r * Dd + (lane & 15) + f * 16] = f2bf(acc[f][j]);
            if ((lane & 15) == 0) { hs[r] = ps; hd[r] = pd; }
        }
    }
}

// ---------------- fused per-node GAT aggregation + BN + ReLU ----------------
template<bool BF16OUT>
__global__ __launch_bounds__(256) void gat_agg_kernel(
    const int* __restrict__ rowptr, const int* __restrict__ ssrc,
    const float* __restrict__ hs, const float* __restrict__ hd,
    const ushort* __restrict__ Hb,
    const float* __restrict__ bias, const float* __restrict__ gamma,
    const float* __restrict__ beta, const float* __restrict__ mean,
    const float* __restrict__ var, void* __restrict__ outv, int N)
{
    const int wid = (blockIdx.x * 256 + threadIdx.x) >> 6;
    if (wid >= N) return;
    const int lane = threadIdx.x & 63;
    const int q = lane >> 4, li = lane & 15;
    const size_t rowO = (size_t)wid * Dd;

    const float hdi = hd[wid];
    float sc0 = hs[wid] + hdi;
    sc0 = sc0 > 0.f ? sc0 : NEG_SLOPE * sc0;
    const float w0 = (q == 0) ? __expf(sc0) : 0.f;

    float acc[8];
    float s = w0;
    {
        uint4 own = *(const uint4*)&Hb[rowO + li * 8];
#pragma unroll
        for (int k = 0; k < 4; ++k) {
            unsigned w = ((const unsigned*)&own)[k];
            acc[2 * k]     = w0 * __uint_as_float(w << 16);
            acc[2 * k + 1] = w0 * __uint_as_float(w & 0xffff0000u);
        }
    }

    const int rs = rowptr[wid];
    const int nv = rowptr[wid + 1] - rs;

    uint4 r0 = make_uint4(0, 0, 0, 0), r1 = make_uint4(0, 0, 0, 0);
    float h0 = 0.f, h1 = 0.f;
    if (q < nv) {
        int sj = ssrc[rs + q];
        h0 = hs[sj];
        r0 = *(const uint4*)&Hb[(size_t)sj * Dd + li * 8];
    }
    if (4 + q < nv) {
        int sj = ssrc[rs + 4 + q];
        h1 = hs[sj];
        r1 = *(const uint4*)&Hb[(size_t)sj * Dd + li * 8];
    }

    const int nit = (nv + 3) >> 2;
    for (int it = 0; it < nit; ++it) {
        float scv = h0 + hdi;
        scv = scv > 0.f ? scv : NEG_SLOPE * scv;
        float ee = (it * 4 + q < nv) ? __expf(scv) : 0.f;
        s += ee;
        uint4 rc = r0;
        r0 = r1; h0 = h1;
        int pn = (it + 2) * 4 + q;
        if (pn < nv) {
            int sj = ssrc[rs + pn];
            h1 = hs[sj];
            r1 = *(const uint4*)&Hb[(size_t)sj * Dd + li * 8];
        }
#pragma unroll
        for (int k = 0; k < 4; ++k) {
            unsigned w = ((const unsigned*)&rc)[k];
            acc[2 * k]     += ee * __uint_as_float(w << 16);
            acc[2 * k + 1] += ee * __uint_as_float(w & 0xffff0000u);
        }
    }

#pragma unroll
    for (int k = 0; k < 8; ++k) {
        acc[k] += __shfl_xor(acc[k], 16);
        acc[k] += __shfl_xor(acc[k], 32);
    }
    s += __shfl_xor(s, 16);
    s += __shfl_xor(s, 32);

    if (q == 0) {
        float inv = 1.0f / s;
        int c0 = li * 8;
        float o[8];
#pragma unroll
        for (int m = 0; m < 8; ++m) {
            float bm = bias[c0 + m], gm = gamma[c0 + m], btm = beta[c0 + m];
            float mnm = mean[c0 + m], vrm = var[c0 + m];
            o[m] = fmaxf((acc[m] * inv + bm - mnm) * (gm * rsqrtf(vrm + BN_EPS)) + btm, 0.f);
        }
        if constexpr (BF16OUT) {
            ushort* out = (ushort*)outv;
            uint4 pk;
#pragma unroll
            for (int k = 0; k < 4; ++k)
                ((unsigned*)&pk)[k] = (unsigned)f2bf(o[2 * k]) | ((unsigned)f2bf(o[2 * k + 1]) << 16);
            *(uint4*)&out[rowO + c0] = pk;
        } else {
            float* out = (float*)outv;
            *(float4*)&out[rowO + c0]     = make_float4(o[0], o[1], o[2], o[3]);
            *(float4*)&out[rowO + c0 + 4] = make_float4(o[4], o[5], o[6], o[7]);
        }
    }
}

extern "C" void kernel_launch(void* const* d_in, const int* in_sizes, int n_in,
                              void* d_out, int out_size, void* d_ws, size_t ws_size,
                              hipStream_t stream)
{
    const float* x     = (const float*)d_in[0];
    const int*   ei    = (const int*)d_in[1];
    const float* Ws    = (const float*)d_in[2];
    const float* a_src = (const float*)d_in[3];
    const float* a_dst = (const float*)d_in[4];
    const float* bias  = (const float*)d_in[5];
    const float* gamma = (const float*)d_in[6];
    const float* beta  = (const float*)d_in[7];
    const float* mean  = (const float*)d_in[8];
    const float* var   = (const float*)d_in[9];
    float* out = (float*)d_out;
    float* ws  = (float*)d_ws;

    const int N = in_sizes[0] / Dd;       // 50000 (< 65536: packed-edge format)
    const int E = in_sizes[1] / 2;
    const int NB = (N + 255) >> 8;        // coarse buckets (<= 256)
    const int* src = ei;
    const int* dst = ei + E;

    float* hs    = ws;                                  // N
    float* hd    = hs + N;                              // N
    ushort* Hb   = (ushort*)(hd + N);                   // N*128 bf16
    ushort* xmid = Hb + (size_t)N * Dd;                 // N*128 bf16
    ushort* WtB  = xmid + (size_t)N * Dd;               // 2*128*128 bf16
    int* rowptr  = (int*)(WtB + 2 * Dd * Dd);           // N+1
    int* cntc    = rowptr + (N + 1);                    // 256
    int* base    = cntc + 256;                          // 257
    int* cursor  = base + 257;                          // 256
    unsigned* gpart = (unsigned*)(cursor + 256);        // E
    int* ssrc    = (int*)(gpart + E);                   // E

    const int gemm_blocks = (N + 63) / 64;
    const int part_blocks = (E + 4095) / 4096;
    const int agg_blocks  = (N * 64 + 255) / 256;

    // ---- CSR build via two-level radix partition (shared by both layers) ----
    wprep_zero_kernel<<<3, 256, 0, stream>>>(Ws, WtB, cntc);
    coarse_hist_kernel<<<256, 256, 0, stream>>>(dst, cntc, E, NB);
    coarse_scan_kernel<<<1, 256, 0, stream>>>(cntc, base, cursor, NB, E);
    partition_kernel<<<part_blocks, 256, 0, stream>>>(src, dst, cursor, gpart, E);
    bucket_csr_kernel<<<NB, 256, 0, stream>>>(gpart, base, rowptr, ssrc, N, NB, E);

    // layer 0: f32 in -> bf16 xmid
    gemm_mfma<false><<<gemm_blocks, 256, 0, stream>>>(
        x, WtB, a_src, a_dst, Hb, hs, hd, N);
    gat_agg_kernel<true><<<agg_blocks, 256, 0, stream>>>(
        rowptr, ssrc, hs, hd, Hb, bias, gamma, beta, mean, var, (void*)xmid, N);

    // layer 1: bf16 in -> f32 out
    gemm_mfma<true><<<gemm_blocks, 256, 0, stream>>>(
        xmid, WtB + (size_t)Dd * Dd, a_src + Dd, a_dst + Dd, Hb, hs, hd, N);
    gat_agg_kernel<false><<<agg_blocks, 256, 0, stream>>>(
        rowptr, ssrc, hs, hd, Hb, bias + Dd, gamma + Dd, beta + Dd,
        mean + Dd, var + Dd, (void*)out, N);
}